// Round 1
// baseline (635.225 us; speedup 1.0000x reference)
//
#include <hip/hip_runtime.h>
#include <stdint.h>

typedef unsigned long long u64;
typedef unsigned int u32;

#define N_MASKS 1536
#define HW 50176           // 224*224
#define WORDS 784          // HW/64
#define NCLS 80
#define POST_NMS_K 768
#define SEG_ELEMS ((size_t)POST_NMS_K * HW)   // 38,535,168
#define KEYPAD 2048
#define NMS_THREADS 256

// ---------------- Kernel 1: bitpack binary masks ----------------
// word w covers pixels [w*64, w*64+64); bit order within a word is arbitrary
// but consistent, which is all popcount(a&b) needs.
__global__ __launch_bounds__(256) void pack_kernel(const float* __restrict__ masks,
                                                   u64* __restrict__ bits) {
    int w = blockIdx.x * blockDim.x + threadIdx.x;
    if (w >= N_MASKS * WORDS) return;
    const float4* p = reinterpret_cast<const float4*>(masks) + (size_t)w * 16;
    u64 b = 0;
#pragma unroll
    for (int t = 0; t < 16; ++t) {
        float4 v = p[t];
        u64 n = (u64)(v.x > 0.5f) | ((u64)(v.y > 0.5f) << 1) |
                ((u64)(v.z > 0.5f) << 2) | ((u64)(v.w > 0.5f) << 3);
        b |= n << (t * 4);
    }
    bits[w] = b;
}

// ---------------- Kernel 2: per-class matrix NMS ----------------
// One block per class. Members gathered in ascending index order (matches triu).
// D[a][b] = I/(2*S_b - I + eps)  (reference's mask_sum[None,:]+mask_sum[None,:] quirk)
// c[b] = max_{a<b} D[a][b];  M[b] = max(0, max_{a<b}(D[a][b]^2 - c[a]^2))
// decay[b] = exp(-M[b]/0.5);  key = (score*decay >= 0.5) ? score : -1
__global__ __launch_bounds__(NMS_THREADS) void nms_kernel(
        const int* __restrict__ labels, const float* __restrict__ scores,
        const float* __restrict__ msum, const u64* __restrict__ bits,
        float* __restrict__ keys) {
    const int cls = blockIdx.x;
    const int tid = threadIdx.x;
    __shared__ int members[N_MASKS];
    __shared__ float Sm[N_MASKS / 4];    // per-class member count is far below N/4=384
    __shared__ float Sc[N_MASKS / 4];
    __shared__ u32 cL[N_MASKS / 4];
    __shared__ u32 ML[N_MASKS / 4];
    __shared__ int tcnt[NMS_THREADS];
    __shared__ int toff[NMS_THREADS];
    __shared__ int mcount;

    // ordered compaction of this class's member indices
    const int PER = N_MASKS / NMS_THREADS;   // 6
    int base = tid * PER;
    int lab[PER];
    int c = 0;
#pragma unroll
    for (int k = 0; k < PER; ++k) { lab[k] = labels[base + k]; c += (lab[k] == cls); }
    tcnt[tid] = c;
    __syncthreads();
    if (tid == 0) {
        int s = 0;
        for (int t = 0; t < NMS_THREADS; ++t) { toff[t] = s; s += tcnt[t]; }
        mcount = s;
    }
    __syncthreads();
    {
        int o = toff[tid];
#pragma unroll
        for (int k = 0; k < PER; ++k)
            if (lab[k] == cls) members[o++] = base + k;
    }
    __syncthreads();
    const int m = mcount;   // expected ~19; LDS arrays sized 384 for safety
    for (int b = tid; b < m; b += NMS_THREADS) {
        int g = members[b];
        Sm[b] = msum[g];
        Sc[b] = scores[g];
        cL[b] = 0u;
        ML[b] = 0u;
    }
    __syncthreads();

    const int npairs = m * (m - 1) / 2;
    const int wid = tid >> 6, lane = tid & 63;
    const int NW = NMS_THREADS / 64;

    // Phase A: compensate c[b] = max_{a<b} D[a][b]
    for (int p = wid; p < npairs; p += NW) {
        int b = (int)((1.0 + sqrt(1.0 + 8.0 * (double)p)) * 0.5);
        while (b * (b - 1) / 2 > p) --b;
        while ((b + 1) * b / 2 <= p) ++b;
        int a = p - b * (b - 1) / 2;
        const u64* pa = bits + (size_t)members[a] * WORDS;
        const u64* pb = bits + (size_t)members[b] * WORDS;
        int I = 0;
        for (int k = lane; k < WORDS; k += 64) I += __popcll(pa[k] & pb[k]);
#pragma unroll
        for (int off = 32; off; off >>= 1) I += __shfl_xor(I, off, 64);
        if (lane == 0) {
            float fI = (float)I;
            float D = fI / (2.0f * Sm[b] - fI + 1e-6f);
            atomicMax(&cL[b], __float_as_uint(D));   // D >= 0: bit order == float order
        }
    }
    __syncthreads();

    // Phase B: M[b] = max(0, max_{a<b}(D^2 - c[a]^2))
    for (int p = wid; p < npairs; p += NW) {
        int b = (int)((1.0 + sqrt(1.0 + 8.0 * (double)p)) * 0.5);
        while (b * (b - 1) / 2 > p) --b;
        while ((b + 1) * b / 2 <= p) ++b;
        int a = p - b * (b - 1) / 2;
        const u64* pa = bits + (size_t)members[a] * WORDS;
        const u64* pb = bits + (size_t)members[b] * WORDS;
        int I = 0;
        for (int k = lane; k < WORDS; k += 64) I += __popcll(pa[k] & pb[k]);
#pragma unroll
        for (int off = 32; off; off >>= 1) I += __shfl_xor(I, off, 64);
        if (lane == 0) {
            float fI = (float)I;
            float D = fI / (2.0f * Sm[b] - fI + 1e-6f);
            float ca = __uint_as_float(cL[a]);
            float v = fmaxf(D * D - ca * ca, 0.0f);
            atomicMax(&ML[b], __float_as_uint(v));
        }
    }
    __syncthreads();

    for (int b = tid; b < m; b += NMS_THREADS) {
        float Mv = __uint_as_float(ML[b]);
        float decay = expf(-2.0f * Mv);              // exp(-M/0.5)
        float dec = Sc[b] * decay;
        keys[members[b]] = (dec >= 0.5f) ? Sc[b] : -1.0f;
    }
}

// ---------------- Kernel 3: bitonic top-k + small outputs ----------------
__global__ __launch_bounds__(1024) void sort_kernel(
        const float* __restrict__ keys, const float* __restrict__ scores,
        const int* __restrict__ labels, const float* __restrict__ factors,
        int* __restrict__ sel, float* __restrict__ out_small) {
    __shared__ u64 k2[KEYPAD];
    const int tid = threadIdx.x;
    for (int i = tid; i < KEYPAD; i += 1024) {
        u64 v = 0;
        if (i < N_MASKS) {
            u32 fb = __float_as_uint(keys[i]);
            u32 od = (fb & 0x80000000u) ? ~fb : (fb | 0x80000000u);  // order-preserving
            v = ((u64)od << 32) | (u32)(~(u32)i);                    // tie -> lower index
        }
        k2[i] = v;
    }
    __syncthreads();
    for (int k = 2; k <= KEYPAD; k <<= 1) {
        for (int j = k >> 1; j > 0; j >>= 1) {
            for (int i = tid; i < KEYPAD; i += 1024) {
                int p = i ^ j;
                if (p > i) {
                    bool desc = ((i & k) == 0);
                    u64 x = k2[i], y = k2[p];
                    if ((x < y) == desc) { k2[i] = y; k2[p] = x; }
                }
            }
            __syncthreads();
        }
    }
    for (int r = tid; r < POST_NMS_K; r += 1024) {
        u64 v = k2[r];
        u32 od = (u32)(v >> 32);
        bool kept = (od >= 0x80000000u);    // key float >= 0  (pads have od==0)
        int idx = (int)(~(u32)v);
        if (kept) {
            sel[r] = idx;
            out_small[r] = scores[idx];
            out_small[POST_NMS_K + r] = (float)labels[idx];
            out_small[2 * POST_NMS_K + r] = factors[idx];
        } else {
            sel[r] = -1;
            out_small[r] = 0.0f;
            out_small[POST_NMS_K + r] = -1.0f;
            out_small[2 * POST_NMS_K + r] = 0.0f;
        }
    }
}

// ---------------- Kernel 4: gather seg rows ----------------
__global__ __launch_bounds__(256) void gather_kernel(const float4* __restrict__ seg,
                                                     const int* __restrict__ sel,
                                                     float4* __restrict__ out) {
    int row = blockIdx.y;
    int col = blockIdx.x * blockDim.x + threadIdx.x;   // 0..12543
    int s = sel[row];
    float4 v = make_float4(0.f, 0.f, 0.f, 0.f);
    if (s >= 0) v = seg[(size_t)s * (HW / 4) + col];
    out[(size_t)row * (HW / 4) + col] = v;
}

extern "C" void kernel_launch(void* const* d_in, const int* in_sizes, int n_in,
                              void* d_out, int out_size, void* d_ws, size_t ws_size,
                              hipStream_t stream) {
    const int* labels = (const int*)d_in[0];
    const float* scores = (const float*)d_in[1];
    const float* factors = (const float*)d_in[2];
    const float* seg = (const float*)d_in[3];
    const float* masks = (const float*)d_in[4];
    const float* msum = (const float*)d_in[5];

    float* out = (float*)d_out;
    // bits scratch lives at the start of d_out's seg region (9.6 MB); it is
    // fully consumed by nms_kernel before gather_kernel overwrites it.
    u64* bits = (u64*)d_out;
    float* keys = (float*)d_ws;                          // 1536 floats
    int* sel = (int*)((char*)d_ws + N_MASKS * sizeof(float)); // 768 ints

    {   // pack
        int total = N_MASKS * WORDS;
        pack_kernel<<<(total + 255) / 256, 256, 0, stream>>>(masks, bits);
    }
    nms_kernel<<<NCLS, NMS_THREADS, 0, stream>>>(labels, scores, msum, bits, keys);
    sort_kernel<<<1, 1024, 0, stream>>>(keys, scores, labels, factors, sel,
                                        out + SEG_ELEMS);
    {   // gather: 50176/4 = 12544 float4 per row; 12544/256 = 49 blocks
        dim3 grid(49, POST_NMS_K);
        gather_kernel<<<grid, 256, 0, stream>>>((const float4*)seg, sel,
                                                (float4*)out);
    }
}

// Round 2
// 282.580 us; speedup vs baseline: 2.2479x; 2.2479x over previous
//
#include <hip/hip_runtime.h>
#include <stdint.h>

typedef unsigned long long u64;
typedef unsigned int u32;

#define N_MASKS 1536
#define HW 50176           // 224*224
#define WORDS 784          // HW/64
#define NCLS 80
#define POST_NMS_K 768
#define SEG_ELEMS ((size_t)POST_NMS_K * HW)   // 38,535,168
#define KEYPAD 2048
#define BITS_BYTES ((size_t)N_MASKS * WORDS * 8)   // 9,633,792

// ---------------- Kernel 1: bitpack via wave ballot ----------------
// Each wave packs 256 consecutive pixels of one mask: lane reads float4
// (4 pixels), 4 ballots produce 4 u64 words. Pixel->bit mapping is a fixed
// permutation, identical for every mask, so popcount(a&b) is unaffected.
__global__ __launch_bounds__(256) void pack_kernel(const float4* __restrict__ masks,
                                                   u64* __restrict__ bits) {
    int gid = blockIdx.x * blockDim.x + threadIdx.x;
    int wave = gid >> 6;                 // group of 256 pixels
    int lane = gid & 63;
    // total groups = N_MASKS * HW/256 = 1536*196
    float4 v = masks[(size_t)wave * 64 + lane];
    u64 b0 = __ballot(v.x > 0.5f);
    u64 b1 = __ballot(v.y > 0.5f);
    u64 b2 = __ballot(v.z > 0.5f);
    u64 b3 = __ballot(v.w > 0.5f);
    if (lane < 4) {
        u64 w = (lane == 0) ? b0 : (lane == 1) ? b1 : (lane == 2) ? b2 : b3;
        bits[(size_t)wave * 4 + lane] = w;
    }
}

// ---------------- Kernel 2: setup — per-class member lists + pair offsets ----
// members: ordered (ascending global index) concatenated per class.
// classBase[81]: member-list prefix; pairOff[81]: pair-count prefix.
__global__ __launch_bounds__(256) void setup_kernel(
        const int* __restrict__ labels,
        int* __restrict__ members, int* __restrict__ classBase,
        int* __restrict__ pairOff, u32* __restrict__ comp, u32* __restrict__ Mv) {
    __shared__ int lab[N_MASKS];
    __shared__ int cnt[NCLS];
    __shared__ int base[NCLS + 1];
    const int tid = threadIdx.x;
    for (int i = tid; i < N_MASKS; i += 256) lab[i] = labels[i];
    __syncthreads();
    if (tid < NCLS) {
        int c = 0;
        for (int i = 0; i < N_MASKS; ++i) c += (lab[i] == tid);
        cnt[tid] = c;
    }
    // init comp/M while waiting
    for (int i = tid; i < N_MASKS; i += 256) { comp[i] = 0u; Mv[i] = 0u; }
    __syncthreads();
    if (tid == 0) {
        int s = 0, ps = 0;
        for (int c = 0; c < NCLS; ++c) {
            base[c] = s; classBase[c] = s;
            pairOff[c] = ps;
            int m = cnt[c];
            s += m; ps += m * (m - 1) / 2;
        }
        base[NCLS] = s; classBase[NCLS] = s; pairOff[NCLS] = ps;
    }
    __syncthreads();
    if (tid < NCLS) {
        int o = base[tid];
        for (int i = 0; i < N_MASKS; ++i)
            if (lab[i] == tid) members[o++] = i;
    }
}

__device__ __forceinline__ int find_class(const int* sPairOff, int p) {
    int lo = 0, hi = NCLS - 1;           // find c: pairOff[c] <= p < pairOff[c+1]
    while (lo < hi) {
        int mid = (lo + hi + 1) >> 1;
        if (sPairOff[mid] <= p) lo = mid; else hi = mid - 1;
    }
    return lo;
}

__device__ __forceinline__ void decode_pair(int pp, int& a, int& b) {
    int bb = (int)((1.0 + sqrt(1.0 + 8.0 * (double)pp)) * 0.5);
    while (bb * (bb - 1) / 2 > pp) --bb;
    while ((bb + 1) * bb / 2 <= pp) ++bb;
    b = bb;
    a = pp - bb * (bb - 1) / 2;
}

// ---------------- Kernel 3: one wave per pair — D and compensate ----------
// D[a][b] = I/(2*S_b - I + eps)  (reference's mask_sum quirk: union = 2*S_col - I)
__global__ __launch_bounds__(256) void pairsD_kernel(
        const int* __restrict__ members, const int* __restrict__ classBase,
        const int* __restrict__ pairOff, const float* __restrict__ msum,
        const u64* __restrict__ bits, float* __restrict__ Dp,
        u32* __restrict__ comp) {
    __shared__ int sPO[NCLS + 1];
    __shared__ int sCB[NCLS + 1];
    const int tid = threadIdx.x;
    if (tid <= NCLS) { sPO[tid] = pairOff[tid]; sCB[tid] = classBase[tid]; }
    __syncthreads();
    const int total = sPO[NCLS];
    const int lane = tid & 63;
    int wid = blockIdx.x * 4 + (tid >> 6);
    const int nw = gridDim.x * 4;
    for (int p = wid; p < total; p += nw) {
        int c = find_class(sPO, p);
        int a, b;
        decode_pair(p - sPO[c], a, b);
        int ga = members[sCB[c] + a];
        int gb = members[sCB[c] + b];
        const u64* pa = bits + (size_t)ga * WORDS;
        const u64* pb = bits + (size_t)gb * WORDS;
        int I = 0;
        for (int k = lane; k < WORDS; k += 64) I += __popcll(pa[k] & pb[k]);
#pragma unroll
        for (int off = 32; off; off >>= 1) I += __shfl_xor(I, off, 64);
        if (lane == 0) {
            float fI = (float)I;
            float D = fI / (2.0f * msum[gb] - fI + 1e-6f);   // D in [0,1]
            Dp[p] = D;
            atomicMax(&comp[gb], __float_as_uint(D));  // non-neg: uint order == float order
        }
    }
}

// ---------------- Kernel 4: one thread per pair — M[b] ----------------
// M[b] = max(0, max_{a<b}(D_ab^2 - c[a]^2));  (row 0 of the matrix guarantees
// the implicit 0 bound, see derivation: c[first member]=0)
__global__ __launch_bounds__(256) void pairsM_kernel(
        const int* __restrict__ members, const int* __restrict__ classBase,
        const int* __restrict__ pairOff, const float* __restrict__ Dp,
        const u32* __restrict__ comp, u32* __restrict__ Mv) {
    __shared__ int sPO[NCLS + 1];
    __shared__ int sCB[NCLS + 1];
    const int tid = threadIdx.x;
    if (tid <= NCLS) { sPO[tid] = pairOff[tid]; sCB[tid] = classBase[tid]; }
    __syncthreads();
    const int total = sPO[NCLS];
    int gid = blockIdx.x * 256 + tid;
    const int stride = gridDim.x * 256;
    for (int p = gid; p < total; p += stride) {
        int c = find_class(sPO, p);
        int a, b;
        decode_pair(p - sPO[c], a, b);
        int ga = members[sCB[c] + a];
        int gb = members[sCB[c] + b];
        float D = Dp[p];
        float ca = __uint_as_float(comp[ga]);
        float v = fmaxf(D * D - ca * ca, 0.0f);
        atomicMax(&Mv[gb], __float_as_uint(v));
    }
}

// ---------------- Kernel 5: keys + bitonic top-k + small outputs ----------
__global__ __launch_bounds__(1024) void sort_kernel(
        const u32* __restrict__ Mv, const float* __restrict__ scores,
        const int* __restrict__ labels, const float* __restrict__ factors,
        int* __restrict__ sel, float* __restrict__ out_small) {
    __shared__ u64 k2[KEYPAD];
    const int tid = threadIdx.x;
    for (int i = tid; i < KEYPAD; i += 1024) {
        u64 v = 0;
        if (i < N_MASKS) {
            float sc = scores[i];
            float decay = __expf(-2.0f * __uint_as_float(Mv[i]));   // exp(-M/sigma)
            float key = (sc * decay >= 0.5f) ? sc : -1.0f;
            u32 fb = __float_as_uint(key);
            u32 od = (fb & 0x80000000u) ? ~fb : (fb | 0x80000000u);  // order-preserving
            v = ((u64)od << 32) | (u32)(~(u32)i);                    // tie -> lower index
        }
        k2[i] = v;
    }
    __syncthreads();
    for (int k = 2; k <= KEYPAD; k <<= 1) {
        for (int j = k >> 1; j > 0; j >>= 1) {
            for (int i = tid; i < KEYPAD; i += 1024) {
                int p = i ^ j;
                if (p > i) {
                    bool desc = ((i & k) == 0);
                    u64 x = k2[i], y = k2[p];
                    if ((x < y) == desc) { k2[i] = y; k2[p] = x; }
                }
            }
            __syncthreads();
        }
    }
    for (int r = tid; r < POST_NMS_K; r += 1024) {
        u64 v = k2[r];
        u32 od = (u32)(v >> 32);
        bool kept = (od >= 0x80000000u);    // key float >= 0 (pads have od==0)
        int idx = (int)(~(u32)v);
        if (kept) {
            sel[r] = idx;
            out_small[r] = scores[idx];
            out_small[POST_NMS_K + r] = (float)labels[idx];
            out_small[2 * POST_NMS_K + r] = factors[idx];
        } else {
            sel[r] = -1;
            out_small[r] = 0.0f;
            out_small[POST_NMS_K + r] = -1.0f;
            out_small[2 * POST_NMS_K + r] = 0.0f;
        }
    }
}

// ---------------- Kernel 6: gather seg rows ----------------
__global__ __launch_bounds__(256) void gather_kernel(const float4* __restrict__ seg,
                                                     const int* __restrict__ sel,
                                                     float4* __restrict__ out) {
    int row = blockIdx.y;
    int col = blockIdx.x * blockDim.x + threadIdx.x;   // 0..12543
    int s = sel[row];
    float4 v = make_float4(0.f, 0.f, 0.f, 0.f);
    if (s >= 0) v = seg[(size_t)s * (HW / 4) + col];
    out[(size_t)row * (HW / 4) + col] = v;
}

extern "C" void kernel_launch(void* const* d_in, const int* in_sizes, int n_in,
                              void* d_out, int out_size, void* d_ws, size_t ws_size,
                              hipStream_t stream) {
    const int* labels = (const int*)d_in[0];
    const float* scores = (const float*)d_in[1];
    const float* factors = (const float*)d_in[2];
    const float* seg = (const float*)d_in[3];
    const float* masks = (const float*)d_in[4];
    const float* msum = (const float*)d_in[5];

    float* out = (float*)d_out;
    // Scratch layout in d_out's seg region (fully overwritten by gather later):
    //   [0, 9.6MB)   packed bits
    //   [9.6MB, ..)  per-pair D values (worst case 1.18M floats = 4.7MB)
    u64* bits = (u64*)d_out;
    float* Dp = (float*)((char*)d_out + BITS_BYTES);

    // d_ws layout (ints/u32): members[1536] classBase[81] pairOff[81]
    //                         comp[1536] Mv[1536] sel[768]  (~22 KB)
    int* members = (int*)d_ws;
    int* classBase = members + N_MASKS;
    int* pairOff = classBase + (NCLS + 1);
    u32* comp = (u32*)(pairOff + (NCLS + 1));
    u32* Mv = comp + N_MASKS;
    int* sel = (int*)(Mv + N_MASKS);

    {   // pack: 1536 masks * 196 wave-groups; 4 waves/block -> 75264 blocks
        int groups = N_MASKS * (HW / 256);
        pack_kernel<<<groups / 4, 256, 0, stream>>>((const float4*)masks, bits);
    }
    setup_kernel<<<1, 256, 0, stream>>>(labels, members, classBase, pairOff,
                                        comp, Mv);
    pairsD_kernel<<<1024, 256, 0, stream>>>(members, classBase, pairOff, msum,
                                            bits, Dp, comp);
    pairsM_kernel<<<128, 256, 0, stream>>>(members, classBase, pairOff, Dp,
                                           comp, Mv);
    sort_kernel<<<1, 1024, 0, stream>>>(Mv, scores, labels, factors, sel,
                                        out + SEG_ELEMS);
    {   // gather: 50176/4 = 12544 float4 per row; 49 blocks x 256 threads
        dim3 grid(49, POST_NMS_K);
        gather_kernel<<<grid, 256, 0, stream>>>((const float4*)seg, sel,
                                                (float4*)out);
    }
}